// Round 10
// baseline (269.551 us; speedup 1.0000x reference)
//
#include <hip/hip_runtime.h>
#include <hip/hip_bf16.h>

// AttentionBlock: GroupNorm -> QKV -> 4-head attention (S=4096, D=64) -> out proj -> +residual
// B=4, C=256, H=W=64, S=4096, N_GROUPS=32, N_HEADS=4, D_K=64

typedef __attribute__((ext_vector_type(8))) short short8;   // 8 bf16 (4 VGPRs) MFMA A/B frag
typedef __attribute__((ext_vector_type(4))) float f32x4;    // 16x16 MFMA C/D frag
typedef __attribute__((ext_vector_type(16))) float f32x16;  // 32x32 MFMA C/D frag

__device__ __forceinline__ unsigned short f2bf(float f) {
    union { float f; unsigned u; } v; v.f = f;
    unsigned r = v.u + 0x7FFF + ((v.u >> 16) & 1);
    return (unsigned short)(r >> 16);
}

__device__ __forceinline__ unsigned cvt_pk_bf16(float lo, float hi) {
    unsigned r;
    asm("v_cvt_pk_bf16_f32 %0, %1, %2" : "=v"(r) : "v"(lo), "v"(hi));
    return r;
}

__device__ __forceinline__ void permswap(unsigned &x, unsigned &y) {
    // x' = [x_lo | y_lo], y' = [x_hi | y_hi]   (vdst hi-half <-> vsrc lo-half)
    asm("v_permlane32_swap_b32 %0, %1" : "+v"(x), "+v"(y));
}

__device__ __forceinline__ float fexp2(float x) {   // D = 2^S0
    float r;
    asm("v_exp_f32 %0, %1" : "=v"(r) : "v"(x));
    return r;
}

__device__ __forceinline__ void gl_lds16(const void* g, void* l) {
    __builtin_amdgcn_global_load_lds(
        (const __attribute__((address_space(1))) void*)(g),
        (__attribute__((address_space(3))) void*)(l), 16, 0, 0);
}

__device__ __forceinline__ f32x16 fzero16() {
    f32x16 z;
    #pragma unroll
    for (int i = 0; i < 16; ++i) z[i] = 0.f;
    return z;
}

// -------- fat kernel: blocks 0-127 GroupNorm stats; blocks 128-319 weight convert --------
__global__ __launch_bounds__(1024) void k_pre(
    const float* __restrict__ x, float* __restrict__ stats,
    const float* __restrict__ wqkv, const float* __restrict__ wout,
    unsigned short* __restrict__ wqkvT, unsigned short* __restrict__ woutT) {
    if (blockIdx.x < 128) {
        int bg = blockIdx.x;                       // b*32+g ; group channels contiguous
        const float4* xp = (const float4*)(x + bg * 32768);
        float s1 = 0.f, s2 = 0.f;
        for (int i = threadIdx.x; i < 8192; i += 1024) {
            float4 v = xp[i];
            s1 += v.x + v.y + v.z + v.w;
            s2 += v.x*v.x + v.y*v.y + v.z*v.z + v.w*v.w;
        }
        #pragma unroll
        for (int off = 32; off; off >>= 1) {
            s1 += __shfl_down(s1, off);
            s2 += __shfl_down(s2, off);
        }
        __shared__ float r1[16], r2[16];
        int wid = threadIdx.x >> 6;
        if ((threadIdx.x & 63) == 0) { r1[wid] = s1; r2[wid] = s2; }
        __syncthreads();
        if (threadIdx.x == 0) {
            float a = 0.f, b = 0.f;
            #pragma unroll
            for (int i = 0; i < 16; ++i) { a += r1[i]; b += r2[i]; }
            float mean = a * (1.f/32768.f);
            float var  = b * (1.f/32768.f) - mean*mean;
            stats[bg*2]   = mean;
            stats[bg*2+1] = rsqrtf(var + 1e-5f);
        }
    } else {
        int i = (blockIdx.x - 128) * 1024 + threadIdx.x;
        if (i < 196608) {                       // w_qkv [256][768] -> [768][256]
            int k = i / 768, n = i - k * 768;
            wqkvT[n*256 + k] = f2bf(wqkv[i]);
        }
        if (i < 65536) {                        // w_out [256][256] -> [256][256]^T
            int k = i >> 8, n = i & 255;
            woutT[n*256 + k] = f2bf(wout[i]);
        }
    }
}

// -------- fused GroupNorm-apply + QKV GEMM --------
// block = 512 thr, 64 s-rows x all 768 outputs. Phase 1: normalize x -> bf16 h-tile in LDS.
// Phase 2: wave = 32 rows x 192 cols (cg = head), so each B-frag feeds two row-tiles.
__global__ __launch_bounds__(512, 2) void k_qkvf(
    const float* __restrict__ x, const float* __restrict__ gamma,
    const float* __restrict__ beta, const float* __restrict__ stats,
    const unsigned short* __restrict__ wT, const float* __restrict__ bqkv,
    unsigned short* __restrict__ q, unsigned short* __restrict__ kk,
    unsigned short* __restrict__ vT) {
    __shared__ unsigned short t[64][72];          // c-slab staging (verified pattern)
    __shared__ unsigned short lds_h[64][272];     // h-tile [s][c], pad->bank spread

    int m0 = blockIdx.x * 64;                     // global row base (b*4096 + s0)
    int b = m0 >> 12;
    int s0 = m0 & 4095;
    int tid = threadIdx.x;

    // Phase 1: 4 slabs of 64 channels
    #pragma unroll
    for (int cb = 0; cb < 4; ++cb) {
        int c0 = cb * 64;
        #pragma unroll
        for (int k = 0; k < 2; ++k) {
            int u = tid + k * 512;                // 1024 units: 64 c x 16 float4-slots
            int cr = u >> 4;
            int sl = (u & 15) * 4;
            int c = c0 + cr;
            float4 v = *(const float4*)&x[(b*256 + c)*4096 + s0 + sl];
            int sg = (b*32 + (c >> 3)) * 2;
            float mean = stats[sg], rstd = stats[sg+1];
            float sa = rstd * gamma[c];
            float sb = beta[c] - mean * sa;
            ushort4 pk;
            pk.x = f2bf(v.x*sa + sb); pk.y = f2bf(v.y*sa + sb);
            pk.z = f2bf(v.z*sa + sb); pk.w = f2bf(v.w*sa + sb);
            *(ushort4*)&t[cr][sl] = pk;
        }
        __syncthreads();
        int sr = tid >> 3;                        // 0..63 s-row
        int cc8 = (tid & 7) * 8;                  // 8 channels per thread
        unsigned rr[4];
        #pragma unroll
        for (int j = 0; j < 4; ++j)
            rr[j] = (unsigned)t[cc8 + 2*j][sr] | ((unsigned)t[cc8 + 2*j + 1][sr] << 16);
        *(uint4*)&lds_h[sr][c0 + cc8] = make_uint4(rr[0], rr[1], rr[2], rr[3]);
        __syncthreads();
    }

    // Phase 2: GEMM 64 x 768, K=256; wave = 32 rows x 192 cols (cg = head)
    int wid = tid >> 6, lane = tid & 63;
    int g = lane >> 4, li = lane & 15;
    int rg = wid & 1, cg = wid >> 1;
    f32x4 acc[2][12];
    #pragma unroll
    for (int rt = 0; rt < 2; ++rt)
        #pragma unroll
        for (int nt = 0; nt < 12; ++nt) acc[rt][nt] = (f32x4){0.f,0.f,0.f,0.f};
    #pragma unroll
    for (int kt = 0; kt < 8; ++kt) {
        short8 a0 = *(const short8*)&lds_h[rg*32 + li][kt*32 + g*8];
        short8 a1 = *(const short8*)&lds_h[rg*32 + 16 + li][kt*32 + g*8];
        #pragma unroll
        for (int nt = 0; nt < 12; ++nt) {
            int n = cg*192 + nt*16 + li;
            short8 bb = *(const short8*)&wT[n*256 + kt*32 + g*8];
            acc[0][nt] = __builtin_amdgcn_mfma_f32_16x16x32_bf16(a0, bb, acc[0][nt], 0, 0, 0);
            acc[1][nt] = __builtin_amdgcn_mfma_f32_16x16x32_bf16(a1, bb, acc[1][nt], 0, 0, 0);
        }
    }
    int bh = b*4 + cg;
    #pragma unroll
    for (int rt = 0; rt < 2; ++rt) {
        int s0w = s0 + rg*32 + rt*16;
        #pragma unroll
        for (int nt = 0; nt < 12; ++nt) {
            int ng = cg*192 + nt*16 + li;
            float bias = bqkv[ng];
            int d = (nt & 3)*16 + li;
            if ((nt >> 2) == 2) {                     // V -> transposed [bh][d][s]
                ushort4 pk;
                pk.x = f2bf(acc[rt][nt][0] + bias); pk.y = f2bf(acc[rt][nt][1] + bias);
                pk.z = f2bf(acc[rt][nt][2] + bias); pk.w = f2bf(acc[rt][nt][3] + bias);
                *(ushort4*)&vT[(bh*64 + d)*4096 + s0w + g*4] = pk;
            } else if ((nt >> 2) == 0) {              // Q (scale 0.125*log2e folded in)
                #pragma unroll
                for (int r = 0; r < 4; ++r)
                    q[(bh*4096 + s0w + g*4 + r)*64 + d] = f2bf((acc[rt][nt][r] + bias) * 0.1803368801f);
            } else {                                  // K
                #pragma unroll
                for (int r = 0; r < 4; ++r)
                    kk[(bh*4096 + s0w + g*4 + r)*64 + d] = f2bf(acc[rt][nt][r] + bias);
            }
        }
    }
}

// ---------------- flash attention, 32x32x16 MFMA, Q=64/wave (2x LDS-operand reuse) -------------
// LDS-BW-bound kernel: each K/V fragment read from LDS now feeds TWO MFMAs (q-blocks A,B).
// block = 4 waves (256 thr): wave (qw, st) = 64 q-rows, even/odd KV stream. l via VALU psum tree.
// Softmax: C-init = -m; speculative exp2 (P<=16 bound, THR check), rare cheap correction.
__global__ __launch_bounds__(256, 2) void k_attn(
    const unsigned short* __restrict__ q, const unsigned short* __restrict__ kk,
    const unsigned short* __restrict__ vT, unsigned short* __restrict__ ao) {
    __shared__ __align__(16) char smem[65536];    // K [buf2][st2][8KB] | V at +32768

    int n = blockIdx.x;                           // 512 blocks; XCD = n & 7
    int qt = n >> 4;
    int bh = ((n & 7) << 1) | ((n >> 3) & 1);     // 2 heads per XCD -> K/V fits 4MB L2
    int tid = threadIdx.x;
    int wid = tid >> 6, lane = tid & 63;
    int qw = wid & 1, st = wid >> 1;
    int hi = lane >> 5, il = lane & 31;
    int swl = (il & 7) << 4;

    int qbase = qt * 128 + qw * 64;
    short8 bqA[4], bqB[4];                        // Q B-frags for q-blocks A,B
    #pragma unroll
    for (int kc = 0; kc < 4; ++kc) {
        bqA[kc] = *(const short8*)&q[(bh*4096 + qbase + il)*64 + kc*16 + hi*8];
        bqB[kc] = *(const short8*)&q[(bh*4096 + qbase + 32 + il)*64 + kc*16 + hi*8];
    }

    // staging: 256 threads x 16B cover half a tile per instr; 2 instrs per 8KB tile
    unsigned p16  = tid * 16;                     // 0..4080
    unsigned row0 = p16 >> 7;                     // 0..31
    unsigned sw   = (row0 & 7) << 4;
    unsigned ks0  = p16 ^ sw;
    unsigned vc0  = (p16 & 127u) ^ sw;
    const char* kbase  = (const char*)kk + (size_t)bh * 524288;
    const char* vbase0 = (const char*)vT + (size_t)(bh*64 + row0) * 8192;
    const char* vbase1 = vbase0 + (size_t)32 * 8192;
    unsigned woff = wid * 1024;                   // wave-uniform LDS base offset

#define STAGE(d, pair) do {                                                   \
    const char* _k0 = kbase + (size_t)(2*(pair)) * 8192;                      \
    const char* _k1 = _k0 + 8192;                                             \
    size_t _v0 = (size_t)(2*(pair)) * 128;                                    \
    size_t _v1 = _v0 + 128;                                                   \
    char* kd0 = smem + ((d)*2+0)*8192 + woff;                                 \
    char* kd1 = smem + ((d)*2+1)*8192 + woff;                                 \
    char* vd0 = smem + 32768 + ((d)*2+0)*8192 + woff;                         \
    char* vd1 = smem + 32768 + ((d)*2+1)*8192 + woff;                         \
    gl_lds16(_k0 + ks0,            kd0);                                      \
    gl_lds16(_k0 + 4096 + ks0,     kd0 + 4096);                               \
    gl_lds16(_k1 + ks0,            kd1);                                      \
    gl_lds16(_k1 + 4096 + ks0,     kd1 + 4096);                               \
    gl_lds16(vbase0 + _v0 + vc0,   vd0);                                      \
    gl_lds16(vbase1 + _v0 + vc0,   vd0 + 4096);                               \
    gl_lds16(vbase0 + _v1 + vc0,   vd1);                                      \
    gl_lds16(vbase1 + _v1 + vc0,   vd1 + 4096);                               \
} while (0)

    f32x16 oA0 = fzero16(), oA1 = fzero16();      // O^T q-block A: d-tiles 0/1
    f32x16 oB0 = fzero16(), oB1 = fzero16();      // O^T q-block B
    float lA = 0.f, lB = 0.f, m_run = 0.f;

    STAGE(0, 0);
    asm volatile("s_waitcnt vmcnt(0)" ::: "memory");
    __builtin_amdgcn_s_barrier();
    asm volatile("" ::: "memory");

    int cur = 0;
    for (int tp = 0; tp < 32; ++tp) {
        if (tp < 31) STAGE(cur ^ 1, tp + 1);       // next-tile DMA lands during compute

        const char* kb = smem + (cur*2 + st) * 8192;
        const char* vb = smem + 32768 + (cur*2 + st) * 8192;

        // S - m via C-init; each ka frag feeds both q-blocks
        float nm = -m_run;
        f32x16 pA0, pA1, pB0, pB1;
        #pragma unroll
        for (int r = 0; r < 16; ++r) { pA0[r] = nm; pA1[r] = nm; pB0[r] = nm; pB1[r] = nm; }
        __builtin_amdgcn_s_setprio(1);
        #pragma unroll
        for (int kc = 0; kc < 4; ++kc) {
            int c = (kc*32 + hi*16) ^ swl;
            short8 ka0 = *(const short8*)(kb + il*128 + c);
            short8 ka1 = *(const short8*)(kb + 4096 + il*128 + c);
            pA0 = __builtin_amdgcn_mfma_f32_32x32x16_bf16(ka0, bqA[kc], pA0, 0, 0, 0);
            pB0 = __builtin_amdgcn_mfma_f32_32x32x16_bf16(ka0, bqB[kc], pB0, 0, 0, 0);
            pA1 = __builtin_amdgcn_mfma_f32_32x32x16_bf16(ka1, bqA[kc], pA1, 0, 0, 0);
            pB1 = __builtin_amdgcn_mfma_f32_32x32x16_bf16(ka1, bqB[kc], pB1, 0, 0, 0);
        }
        __builtin_amdgcn_s_setprio(0);

        // speculative P = exp2(S - m_run)
        #pragma unroll
        for (int r = 0; r < 16; ++r) {
            pA0[r] = fexp2(pA0[r]); pA1[r] = fexp2(pA1[r]);
            pB0[r] = fexp2(pB0[r]); pB1[r] = fexp2(pB1[r]);
        }
        // Pmax tree over 64 values; rescale only if P would exceed 2^4
        float mm[8];
        #pragma unroll
        for (int r = 0; r < 8; ++r) {
            float a = fmaxf(fmaxf(pA0[2*r], pA0[2*r+1]), fmaxf(pA1[2*r], pA1[2*r+1]));
            float b = fmaxf(fmaxf(pB0[2*r], pB0[2*r+1]), fmaxf(pB1[2*r], pB1[2*r+1]));
            mm[r] = fmaxf(a, b);
        }
        float pm = fmaxf(fmaxf(fmaxf(mm[0], mm[1]), fmaxf(mm[2], mm[3])),
                         fmaxf(fmaxf(mm[4], mm[5]), fmaxf(mm[6], mm[7])));
        if (__any(pm > 16.f)) {                   // rare
            pm = fmaxf(pm, __shfl_xor(pm, 32));
            float fac = 1.f / pm;
            m_run += log2f(pm);
            lA *= fac; lB *= fac;
            #pragma unroll
            for (int r = 0; r < 16; ++r) {
                oA0[r] *= fac; oA1[r] *= fac; oB0[r] *= fac; oB1[r] *= fac;
                pA0[r] *= fac; pA1[r] *= fac; pB0[r] *= fac; pB1[r] *= fac;
            }
        }
        // l: psum trees (VALU has slack; saves the ones-MFMA)
        {
            float a8[8], b8[8];
            #pragma unroll
            for (int r = 0; r < 8; ++r) {
                a8[r] = (pA0[2*r] + pA0[2*r+1]) + (pA1[2*r] + pA1[2*r+1]);
                b8[r] = (pB0[2*r] + pB0[2*r+1]) + (pB1[2*r] + pB1[2*r+1]);
            }
            float psA = ((a8[0]+a8[1]) + (a8[2]+a8[3])) + ((a8[4]+a8[5]) + (a8[6]+a8[7]));
            float psB = ((b8[0]+b8[1]) + (b8[2]+b8[3])) + ((b8[4]+b8[5]) + (b8[6]+b8[7]));
            psA += __shfl_xor(psA, 32);
            psB += __shfl_xor(psB, 32);
            lA += psA; lB += psB;
        }

        // pack P per q-block per jc, fused with PV; each V-frag feeds both q-blocks
        __builtin_amdgcn_s_setprio(1);
        #pragma unroll
        for (int jc = 0; jc < 4; ++jc) {
            const int hh = jc & 1;
            float eA0, eA1, eA2, eA3, eA4, eA5, eA6, eA7;
            float eB0, eB1, eB2, eB3, eB4, eB5, eB6, eB7;
            if (jc < 2) {
                eA0=pA0[hh*8+0]; eA1=pA0[hh*8+1]; eA2=pA0[hh*8+2]; eA3=pA0[hh*8+3];
                eA4=pA0[hh*8+4]; eA5=pA0[hh*8+5]; eA6=pA0[hh*8+6]; eA7=pA0[hh*8+7];
                eB0=pB0[hh*8+0]; eB1=pB0[hh*8+1]; eB2=pB0[hh*8+2]; eB3=pB0[hh*8+3];
                eB4=pB0[hh*8+4]; eB5=pB0[hh*8+5]; eB6=pB0[hh*8+6]; eB7=pB0[hh*8+7];
            } else {
                eA0=pA1[hh*8+0]; eA1=pA1[hh*8+1]; eA2=pA1[hh*8+2]; eA3=pA1[hh*8+3];
                eA4=pA1[hh*8+4]; eA5=pA1[hh*8+5]; eA6=pA1[hh*8+6]; eA7=pA1[hh*8+7];
                eB0=pB1[hh*8+0]; eB1=pB1[hh*8+1]; eB2=pB1[hh*8+2]; eB3=pB1[hh*8+3];
                eB4=pB1[hh*8+4]; eB5=pB1[hh*8+5]; eB6=pB1[hh*8+6]; eB7=pB1[hh*8+7];
            }
            unsigned a0 = cvt_pk_bf16(eA0, eA1), b0 = cvt_pk_bf16(eA2, eA3);
            unsigned c0 = cvt_pk_bf16(eA4, eA5), d0 = cvt_pk_bf16(eA6, eA7);
            permswap(a0, c0); permswap(b0, d0);
            unsigned a1 = cvt_pk_bf16(eB0, eB1), b1 = cvt_pk_bf16(eB2, eB3);
            unsigned c1 = cvt_pk_bf16(eB4, eB5), d1 = cvt_pk_bf16(eB6, eB7);
            permswap(a1, c1); permswap(b1, d1);
            union { unsigned u[4]; short8 s8; } pbA, pbB;
            pbA.u[0]=a0; pbA.u[1]=b0; pbA.u[2]=c0; pbA.u[3]=d0;
            pbB.u[0]=a1; pbB.u[1]=b1; pbB.u[2]=c1; pbB.u[3]=d1;
            int co = (jc*32 + hi*16) ^ swl;
            short8 va0 = *(const short8*)(vb + il*128 + co);
            short8 va1 = *(const short8*)(vb + 4096 + il*128 + co);
            oA0 = __builtin_amdgcn_mfma_f32_32x32x16_bf16(va0, pbA.s8, oA0, 0, 0, 0);
            oB0 = __builtin_amdgcn_mfma_f32_32x32x16_bf16(va0, pbB.s8, oB0, 0, 0, 0);
            oA1 = __builtin_amdgcn_mfma_f32_32x32x16_bf16(va1, pbA.s8, oA1, 0, 0, 0);
            oB1 = __builtin_amdgcn_mfma_f32_32x32x16_bf16(va1, pbB.s8, oB1, 0, 0, 0);
        }
        __builtin_amdgcn_s_setprio(0);

        if (tp < 31) asm volatile("s_waitcnt vmcnt(0)" ::: "memory");
        asm volatile("" ::: "memory");
        __builtin_amdgcn_s_barrier();             // single barrier per tile
        asm volatile("" ::: "memory");
        cur ^= 1;
    }
#undef STAGE

    // combine the two KV streams: st=1 writes partials, st=0 merges + outputs (exact flash)
    float* red = (float*)smem;                    // 256 slots x 34 floats = 34.8 KB (KV dead)
    int b = bh >> 2, hh = bh & 3;
    if (st == 1) {
        int s0 = ((qw*2 + 0)*64 + lane) * 34;
        int s1 = ((qw*2 + 1)*64 + lane) * 34;
        #pragma unroll
        for (int r = 0; r < 16; ++r) {
            red[s0 + r] = oA0[r]; red[s0 + 16 + r] = oA1[r];
            red[s1 + r] = oB0[r]; red[s1 + 16 + r] = oB1[r];
        }
        red[s0 + 32] = lA; red[s0 + 33] = m_run;
        red[s1 + 32] = lB; red[s1 + 33] = m_run;
    }
    __syncthreads();
    if (st == 0) {
        #pragma unroll
        for (int qb = 0; qb < 2; ++qb) {
            int slot = ((qw*2 + qb)*64 + lane) * 34;
            float myl = qb ? lB : lA;
            float m1 = red[slot + 33], l1 = red[slot + 32];
            float m = fmaxf(m_run, m1);
            float f0 = fexp2(m_run - m), f1 = fexp2(m1 - m);
            float inv = 1.f / (myl * f0 + l1 * f1);
            float a0 = f0 * inv, a1 = f1 * inv;
            int s = qbase + qb*32 + il;
            unsigned short* aop = &ao[((size_t)(b*4096 + s))*256 + hh*64];
            #pragma unroll
            for (int rr = 0; rr < 4; ++rr) {
                float o0v[4], o1v[4];
                #pragma unroll
                for (int r = 0; r < 4; ++r) {
                    o0v[r] = (qb ? oB0[rr*4+r] : oA0[rr*4+r]) * a0 + red[slot + rr*4+r] * a1;
                    o1v[r] = (qb ? oB1[rr*4+r] : oA1[rr*4+r]) * a0 + red[slot + 16 + rr*4+r] * a1;
                }
                ushort4 pk0, pk1;
                pk0.x = f2bf(o0v[0]); pk0.y = f2bf(o0v[1]); pk0.z = f2bf(o0v[2]); pk0.w = f2bf(o0v[3]);
                pk1.x = f2bf(o1v[0]); pk1.y = f2bf(o1v[1]); pk1.z = f2bf(o1v[2]); pk1.w = f2bf(o1v[3]);
                *(ushort4*)&aop[rr*8 + hi*4] = pk0;
                *(ushort4*)&aop[32 + rr*8 + hi*4] = pk1;
            }
        }
    }
}

// ------- out GEMM + bias + residual: 64 rows x 256 cols per block, coalesced epilogue -------
__global__ __launch_bounds__(512) void k_out(
    const unsigned short* __restrict__ ao, const unsigned short* __restrict__ wT,
    const float* __restrict__ bout, const float* __restrict__ x,
    float* __restrict__ out) {
    __shared__ float lds_fT[256][68];             // [c][s+pad]: 69.6 KB, rows 16B-aligned
    int mt = blockIdx.x;                          // 256 blocks x 64 rows
    int tid = threadIdx.x;
    int wid = tid >> 6, lane = tid & 63;
    int g = lane >> 4, li = lane & 15;
    int rg = wid & 3, ch = wid >> 2;              // wave = 16 rows x 128 cols
    int m0 = mt * 64;
    int row = m0 + rg*16 + li;
    f32x4 acc[8];
    #pragma unroll
    for (int nt = 0; nt < 8; ++nt) acc[nt] = (f32x4){0.f,0.f,0.f,0.f};
    #pragma unroll
    for (int kt = 0; kt < 8; ++kt) {
        short8 a = *(const short8*)&ao[row*256 + kt*32 + g*8];
        #pragma unroll
        for (int nt = 0; nt < 8; ++nt) {
            int nn = ch*128 + nt*16 + li;
            short8 b = *(const short8*)&wT[nn*256 + kt*32 + g*8];
            acc[nt] = __builtin_amdgcn_mfma_f32_16x16x32_bf16(a, b, acc[nt], 0, 0, 0);
        }
    }
    #pragma unroll
    for (int nt = 0; nt < 8; ++nt) {
        int c = ch*128 + nt*16 + li;
        float bias = bout[c];
        #pragma unroll
        for (int r = 0; r < 4; ++r)
            lds_fT[c][rg*16 + g*4 + r] = acc[nt][r] + bias;
    }
    __syncthreads();
    int b = m0 >> 12;
    int s0 = m0 & 4095;
    #pragma unroll
    for (int p = 0; p < 8; ++p) {
        int c = p*32 + (tid >> 4);
        int sl = (tid & 15) * 4;
        float4 t = *(const float4*)&lds_fT[c][sl];
        int base = (b*256 + c)*4096 + s0 + sl;
        float4 xr = *(const float4*)&x[base];
        t.x += xr.x; t.y += xr.y; t.z += xr.z; t.w += xr.w;
        *(float4*)&out[base] = t;
    }
}

extern "C" void kernel_launch(void* const* d_in, const int* in_sizes, int n_in,
                              void* d_out, int out_size, void* d_ws, size_t ws_size,
                              hipStream_t stream) {
    (void)in_sizes; (void)n_in; (void)out_size; (void)ws_size;
    const float* x     = (const float*)d_in[0];
    const float* gamma = (const float*)d_in[1];
    const float* beta  = (const float*)d_in[2];
    const float* wqkv  = (const float*)d_in[3];
    const float* bqkv  = (const float*)d_in[4];
    const float* wout  = (const float*)d_in[5];
    const float* bout  = (const float*)d_in[6];
    float* out = (float*)d_out;

    char* ws = (char*)d_ws;
    unsigned short* q     = (unsigned short*)(ws + (8u<<20));         // 8 MB  [bh][S][64]
    unsigned short* kk    = (unsigned short*)(ws + (16u<<20));        // 8 MB  [bh][S][64]
    unsigned short* vT    = (unsigned short*)(ws + (24u<<20));        // 8 MB  [bh][64][S]
    unsigned short* ao    = (unsigned short*)(ws + (32u<<20));        // 8 MB  [B*S][256]
    unsigned short* wqkvT = (unsigned short*)(ws + (40u<<20));        // 384 KB [768][256]
    unsigned short* woutT = (unsigned short*)(ws + (40u<<20) + 393216);// 128 KB [256][256]
    float*          stats = (float*)(ws + (40u<<20) + 524288);        // 1 KB

    k_pre<<<320, 1024, 0, stream>>>(x, stats, wqkv, wout, wqkvT, woutT);
    k_qkvf<<<256, 512, 0, stream>>>(x, gamma, beta, stats, wqkvT, bqkv, q, kk, vT);
    k_attn<<<dim3(512), 256, 0, stream>>>(q, kk, vT, ao);
    k_out<<<dim3(256), 512, 0, stream>>>(ao, woutT, bout, x, out);
}

// Round 11
// 150.595 us; speedup vs baseline: 1.7899x; 1.7899x over previous
//
#include <hip/hip_runtime.h>
#include <hip/hip_bf16.h>

// AttentionBlock: GroupNorm -> QKV -> 4-head attention (S=4096, D=64) -> out proj -> +residual
// B=4, C=256, H=W=64, S=4096, N_GROUPS=32, N_HEADS=4, D_K=64

typedef __attribute__((ext_vector_type(8))) short short8;   // 8 bf16 (4 VGPRs) MFMA A/B frag
typedef __attribute__((ext_vector_type(4))) float f32x4;    // 16x16 MFMA C/D frag
typedef __attribute__((ext_vector_type(16))) float f32x16;  // 32x32 MFMA C/D frag

__device__ __forceinline__ unsigned short f2bf(float f) {
    union { float f; unsigned u; } v; v.f = f;
    unsigned r = v.u + 0x7FFF + ((v.u >> 16) & 1);
    return (unsigned short)(r >> 16);
}

__device__ __forceinline__ unsigned cvt_pk_bf16(float lo, float hi) {
    unsigned r;
    asm("v_cvt_pk_bf16_f32 %0, %1, %2" : "=v"(r) : "v"(lo), "v"(hi));
    return r;
}

__device__ __forceinline__ void permswap(unsigned &x, unsigned &y) {
    // x' = [x_lo | y_lo], y' = [x_hi | y_hi]   (vdst hi-half <-> vsrc lo-half)
    asm("v_permlane32_swap_b32 %0, %1" : "+v"(x), "+v"(y));
}

__device__ __forceinline__ float fexp2(float x) {   // D = 2^S0
    float r;
    asm("v_exp_f32 %0, %1" : "=v"(r) : "v"(x));
    return r;
}

__device__ __forceinline__ void gl_lds16(const void* g, void* l) {
    __builtin_amdgcn_global_load_lds(
        (const __attribute__((address_space(1))) void*)(g),
        (__attribute__((address_space(3))) void*)(l), 16, 0, 0);
}

__device__ __forceinline__ f32x16 fzero16() {
    f32x16 z;
    #pragma unroll
    for (int i = 0; i < 16; ++i) z[i] = 0.f;
    return z;
}

// -------- fat kernel: blocks 0-127 GroupNorm stats; blocks 128-319 weight convert --------
__global__ __launch_bounds__(1024) void k_pre(
    const float* __restrict__ x, float* __restrict__ stats,
    const float* __restrict__ wqkv, const float* __restrict__ wout,
    unsigned short* __restrict__ wqkvT, unsigned short* __restrict__ woutT) {
    if (blockIdx.x < 128) {
        int bg = blockIdx.x;                       // b*32+g ; group channels contiguous
        const float4* xp = (const float4*)(x + bg * 32768);
        float s1 = 0.f, s2 = 0.f;
        for (int i = threadIdx.x; i < 8192; i += 1024) {
            float4 v = xp[i];
            s1 += v.x + v.y + v.z + v.w;
            s2 += v.x*v.x + v.y*v.y + v.z*v.z + v.w*v.w;
        }
        #pragma unroll
        for (int off = 32; off; off >>= 1) {
            s1 += __shfl_down(s1, off);
            s2 += __shfl_down(s2, off);
        }
        __shared__ float r1[16], r2[16];
        int wid = threadIdx.x >> 6;
        if ((threadIdx.x & 63) == 0) { r1[wid] = s1; r2[wid] = s2; }
        __syncthreads();
        if (threadIdx.x == 0) {
            float a = 0.f, b = 0.f;
            #pragma unroll
            for (int i = 0; i < 16; ++i) { a += r1[i]; b += r2[i]; }
            float mean = a * (1.f/32768.f);
            float var  = b * (1.f/32768.f) - mean*mean;
            stats[bg*2]   = mean;
            stats[bg*2+1] = rsqrtf(var + 1e-5f);
        }
    } else {
        int i = (blockIdx.x - 128) * 1024 + threadIdx.x;
        if (i < 196608) {                       // w_qkv [256][768] -> [768][256]
            int k = i / 768, n = i - k * 768;
            wqkvT[n*256 + k] = f2bf(wqkv[i]);
        }
        if (i < 65536) {                        // w_out [256][256] -> [256][256]^T
            int k = i >> 8, n = i & 255;
            woutT[n*256 + k] = f2bf(wout[i]);
        }
    }
}

// -------- fused GroupNorm-apply + QKV GEMM --------
// block = 512 thr, 64 s-rows x all 768 outputs. Phase 1: normalize x -> bf16 h-tile in LDS.
// Phase 2: wave = 32 rows x 192 cols (cg = head), so each B-frag feeds two row-tiles.
__global__ __launch_bounds__(512, 2) void k_qkvf(
    const float* __restrict__ x, const float* __restrict__ gamma,
    const float* __restrict__ beta, const float* __restrict__ stats,
    const unsigned short* __restrict__ wT, const float* __restrict__ bqkv,
    unsigned short* __restrict__ q, unsigned short* __restrict__ kk,
    unsigned short* __restrict__ vT) {
    __shared__ unsigned short t[64][72];          // c-slab staging (verified pattern)
    __shared__ unsigned short lds_h[64][272];     // h-tile [s][c], pad->bank spread

    int m0 = blockIdx.x * 64;                     // global row base (b*4096 + s0)
    int b = m0 >> 12;
    int s0 = m0 & 4095;
    int tid = threadIdx.x;

    // Phase 1: 4 slabs of 64 channels
    #pragma unroll
    for (int cb = 0; cb < 4; ++cb) {
        int c0 = cb * 64;
        #pragma unroll
        for (int k = 0; k < 2; ++k) {
            int u = tid + k * 512;                // 1024 units: 64 c x 16 float4-slots
            int cr = u >> 4;
            int sl = (u & 15) * 4;
            int c = c0 + cr;
            float4 v = *(const float4*)&x[(b*256 + c)*4096 + s0 + sl];
            int sg = (b*32 + (c >> 3)) * 2;
            float mean = stats[sg], rstd = stats[sg+1];
            float sa = rstd * gamma[c];
            float sb = beta[c] - mean * sa;
            ushort4 pk;
            pk.x = f2bf(v.x*sa + sb); pk.y = f2bf(v.y*sa + sb);
            pk.z = f2bf(v.z*sa + sb); pk.w = f2bf(v.w*sa + sb);
            *(ushort4*)&t[cr][sl] = pk;
        }
        __syncthreads();
        int sr = tid >> 3;                        // 0..63 s-row
        int cc8 = (tid & 7) * 8;                  // 8 channels per thread
        unsigned rr[4];
        #pragma unroll
        for (int j = 0; j < 4; ++j)
            rr[j] = (unsigned)t[cc8 + 2*j][sr] | ((unsigned)t[cc8 + 2*j + 1][sr] << 16);
        *(uint4*)&lds_h[sr][c0 + cc8] = make_uint4(rr[0], rr[1], rr[2], rr[3]);
        __syncthreads();
    }

    // Phase 2: GEMM 64 x 768, K=256; wave = 32 rows x 192 cols (cg = head)
    int wid = tid >> 6, lane = tid & 63;
    int g = lane >> 4, li = lane & 15;
    int rg = wid & 1, cg = wid >> 1;
    f32x4 acc[2][12];
    #pragma unroll
    for (int rt = 0; rt < 2; ++rt)
        #pragma unroll
        for (int nt = 0; nt < 12; ++nt) acc[rt][nt] = (f32x4){0.f,0.f,0.f,0.f};
    #pragma unroll
    for (int kt = 0; kt < 8; ++kt) {
        short8 a0 = *(const short8*)&lds_h[rg*32 + li][kt*32 + g*8];
        short8 a1 = *(const short8*)&lds_h[rg*32 + 16 + li][kt*32 + g*8];
        #pragma unroll
        for (int nt = 0; nt < 12; ++nt) {
            int n = cg*192 + nt*16 + li;
            short8 bb = *(const short8*)&wT[n*256 + kt*32 + g*8];
            acc[0][nt] = __builtin_amdgcn_mfma_f32_16x16x32_bf16(a0, bb, acc[0][nt], 0, 0, 0);
            acc[1][nt] = __builtin_amdgcn_mfma_f32_16x16x32_bf16(a1, bb, acc[1][nt], 0, 0, 0);
        }
    }
    int bh = b*4 + cg;
    #pragma unroll
    for (int rt = 0; rt < 2; ++rt) {
        int s0w = s0 + rg*32 + rt*16;
        #pragma unroll
        for (int nt = 0; nt < 12; ++nt) {
            int ng = cg*192 + nt*16 + li;
            float bias = bqkv[ng];
            int d = (nt & 3)*16 + li;
            if ((nt >> 2) == 2) {                     // V -> transposed [bh][d][s]
                ushort4 pk;
                pk.x = f2bf(acc[rt][nt][0] + bias); pk.y = f2bf(acc[rt][nt][1] + bias);
                pk.z = f2bf(acc[rt][nt][2] + bias); pk.w = f2bf(acc[rt][nt][3] + bias);
                *(ushort4*)&vT[(bh*64 + d)*4096 + s0w + g*4] = pk;
            } else if ((nt >> 2) == 0) {              // Q (scale 0.125*log2e folded in)
                #pragma unroll
                for (int r = 0; r < 4; ++r)
                    q[(bh*4096 + s0w + g*4 + r)*64 + d] = f2bf((acc[rt][nt][r] + bias) * 0.1803368801f);
            } else {                                  // K
                #pragma unroll
                for (int r = 0; r < 4; ++r)
                    kk[(bh*4096 + s0w + g*4 + r)*64 + d] = f2bf(acc[rt][nt][r] + bias);
            }
        }
    }
}

// ---------------- flash attention, 32x32x16 MFMA, KV-stream split (R9-proven version) ----------
// Softmax: C-init = -m folds the subtract into the QK MFMA; speculative exp2 with stale max
// (bound P <= 16 via THR=4 on Pmax), rare correction; l via ones-MFMA on the matrix pipe.
__global__ __launch_bounds__(512, 4) void k_attn(
    const unsigned short* __restrict__ q, const unsigned short* __restrict__ kk,
    const unsigned short* __restrict__ vT, unsigned short* __restrict__ ao) {
    __shared__ __align__(16) char smem[65536];    // [dbuf][stream] K 8KB x4 | V 8KB x4

    int n = blockIdx.x;                           // 512 blocks; XCD = n & 7 (round-robin dispatch)
    int qt = n >> 4;
    int bh = ((n & 7) << 1) | ((n >> 3) & 1);     // 2 heads per XCD -> K/V fits 4MB L2
    int tid = threadIdx.x;
    int wid = tid >> 6, lane = tid & 63;
    int qw = wid & 3, st = wid >> 2;
    int hi = lane >> 5, il = lane & 31;
    int swl = (il & 7) << 4;

    int qbase = qt * 128 + qw * 32;
    int qrow = bh * 4096 + qbase + il;
    short8 bq[4];                                 // Q B-frags: col=il, k=kc*16+hi*8..
    #pragma unroll
    for (int kc = 0; kc < 4; ++kc)
        bq[kc] = *(const short8*)&q[qrow*64 + kc*16 + hi*8];

    short8 ones;                                  // all-ones bf16 A-frag for the l-MFMA
    #pragma unroll
    for (int i = 0; i < 8; ++i) ones[i] = (short)0x3F80;

    // staging geometry: 512 threads cover one 8KB tile (16B each)
    unsigned p16  = tid * 16;
    unsigned row0 = p16 >> 7;                     // 0..63
    unsigned sw   = (row0 & 7) << 4;
    unsigned ks0  = p16 ^ sw;                     // K tile-local swizzled source byte
    unsigned vc0  = (p16 & 127u) ^ sw;            // V column byte within row
    const char* kbase = (const char*)kk + (size_t)bh * 524288;
    const char* vbase = (const char*)vT + (size_t)(bh*64 + row0) * 8192;
    unsigned woff = wid * 1024;

#define STAGE_PAIR(d, pair) do {                                             \
    const char* _k0 = kbase + (size_t)(2*(pair)) * 8192;                     \
    size_t _vo = (size_t)(2*(pair)) * 128;                                   \
    gl_lds16(_k0 + ks0,              smem + ((d)*2+0)*8192 + woff);          \
    gl_lds16(_k0 + 8192 + ks0,       smem + ((d)*2+1)*8192 + woff);          \
    gl_lds16(vbase + _vo + vc0,       smem + 32768 + ((d)*2+0)*8192 + woff); \
    gl_lds16(vbase + _vo + 128 + vc0, smem + 32768 + ((d)*2+1)*8192 + woff); \
} while (0)

    f32x16 o0 = fzero16(), o1 = fzero16(), accl = fzero16();
    float m_run = 0.f;                            // stale-max in exp2 domain; P <= 16 guaranteed

    STAGE_PAIR(0, 0);
    asm volatile("s_waitcnt vmcnt(0)" ::: "memory");
    __builtin_amdgcn_s_barrier();
    asm volatile("" ::: "memory");

    int cur = 0;
    for (int tp = 0; tp < 32; ++tp) {
        if (tp < 31) STAGE_PAIR(cur ^ 1, tp + 1);  // issue next-tile DMA; lands during compute

        const char* kb = smem + (cur*2 + st) * 8192;
        const char* vb = smem + 32768 + (cur*2 + st) * 8192;

        // (S - m) directly out of the MFMA: C-init = -m_run
        float nm = -m_run;
        f32x16 p0, p1;
        #pragma unroll
        for (int r = 0; r < 16; ++r) { p0[r] = nm; p1[r] = nm; }
        __builtin_amdgcn_s_setprio(1);
        #pragma unroll
        for (int kc = 0; kc < 4; ++kc) {
            int c = (kc*32 + hi*16) ^ swl;
            short8 ka0 = *(const short8*)(kb + il*128 + c);
            short8 ka1 = *(const short8*)(kb + 4096 + il*128 + c);
            p0 = __builtin_amdgcn_mfma_f32_32x32x16_bf16(ka0, bq[kc], p0, 0, 0, 0);
            p1 = __builtin_amdgcn_mfma_f32_32x32x16_bf16(ka1, bq[kc], p1, 0, 0, 0);
        }
        __builtin_amdgcn_s_setprio(0);

        // speculative P = exp2(S - m_run), in place
        #pragma unroll
        for (int r = 0; r < 16; ++r) {
            p0[r] = fexp2(p0[r]);
            p1[r] = fexp2(p1[r]);
        }
        // Pmax tree (depth 5); rescale only if P would exceed 2^4
        float m8[8];
        #pragma unroll
        for (int r = 0; r < 8; ++r)
            m8[r] = fmaxf(fmaxf(p0[2*r], p0[2*r+1]), fmaxf(p1[2*r], p1[2*r+1]));
        float pm = fmaxf(fmaxf(fmaxf(m8[0], m8[1]), fmaxf(m8[2], m8[3])),
                         fmaxf(fmaxf(m8[4], m8[5]), fmaxf(m8[6], m8[7])));
        if (__any(pm > 16.f)) {                   // rare: max grew by > 4 (exp2 domain)
            pm = fmaxf(pm, __shfl_xor(pm, 32));   // row max across lane halves
            float fac = 1.f / pm;
            m_run += log2f(pm);
            accl[0] *= fac;                       // only element 0 is ever read
            #pragma unroll
            for (int r = 0; r < 16; ++r) {
                o0[r] *= fac; o1[r] *= fac;
                p0[r] *= fac; p1[r] *= fac;
            }
        }

        // pack P -> bf16 B-frags (cvt_pk + permlane32_swap) fused with PV + l MFMAs
        __builtin_amdgcn_s_setprio(1);
        #pragma unroll
        for (int jc = 0; jc < 4; ++jc) {
            const int hh = jc & 1;
            float e0, e1, e2, e3, e4, e5, e6, e7;
            if (jc < 2) {
                e0 = p0[hh*8+0]; e1 = p0[hh*8+1]; e2 = p0[hh*8+2]; e3 = p0[hh*8+3];
                e4 = p0[hh*8+4]; e5 = p0[hh*8+5]; e6 = p0[hh*8+6]; e7 = p0[hh*8+7];
            } else {
                e0 = p1[hh*8+0]; e1 = p1[hh*8+1]; e2 = p1[hh*8+2]; e3 = p1[hh*8+3];
                e4 = p1[hh*8+4]; e5 = p1[hh*8+5]; e6 = p1[hh*8+6]; e7 = p1[hh*8+7];
            }
            unsigned a = cvt_pk_bf16(e0, e1);
            unsigned b = cvt_pk_bf16(e2, e3);
            unsigned c = cvt_pk_bf16(e4, e5);
            unsigned d = cvt_pk_bf16(e6, e7);
            permswap(a, c);                       // -> [a_lo|c_lo], [a_hi|c_hi]
            permswap(b, d);
            union { unsigned u[4]; short8 s8; } pb;
            pb.u[0] = a; pb.u[1] = b; pb.u[2] = c; pb.u[3] = d;
            int co = (jc*32 + hi*16) ^ swl;
            short8 va0 = *(const short8*)(vb + il*128 + co);
            short8 va1 = *(const short8*)(vb + 4096 + il*128 + co);
            o0   = __builtin_amdgcn_mfma_f32_32x32x16_bf16(va0, pb.s8, o0, 0, 0, 0);
            o1   = __builtin_amdgcn_mfma_f32_32x32x16_bf16(va1, pb.s8, o1, 0, 0, 0);
            accl = __builtin_amdgcn_mfma_f32_32x32x16_bf16(ones, pb.s8, accl, 0, 0, 0);
        }
        __builtin_amdgcn_s_setprio(0);

        if (tp < 31) asm volatile("s_waitcnt vmcnt(0)" ::: "memory");  // next tile landed
        asm volatile("" ::: "memory");
        __builtin_amdgcn_s_barrier();             // single barrier per tile
        asm volatile("" ::: "memory");
        cur ^= 1;
    }
#undef STAGE_PAIR

    float l_loc = accl[0];                        // full row sum (MFMA k-dim spans both halves)

    // combine the two KV streams (each with its own max): st=1 writes, st=0 merges + outputs
    float* red = (float*)smem;                    // 256 slots x 34 floats = 34 KB (dead K/V region)
    int slot = ((qw*64 + lane) * 34);
    if (st == 1) {
        #pragma unroll
        for (int r = 0; r < 16; ++r) { red[slot + r] = o0[r]; red[slot + 16 + r] = o1[r]; }
        red[slot + 32] = l_loc;
        red[slot + 33] = m_run;
    }
    __syncthreads();
    if (st == 0) {
        float m1 = red[slot + 33], l1 = red[slot + 32];
        float m = fmaxf(m_run, m1);
        float f0 = fexp2(m_run - m), f1 = fexp2(m1 - m);
        float inv = 1.f / (l_loc * f0 + l1 * f1);
        float a0 = f0 * inv, a1 = f1 * inv;
        int b = bh >> 2, hh = bh & 3;
        int s = qbase + il;
        unsigned short* aop = &ao[((size_t)(b*4096 + s))*256 + hh*64];
        #pragma unroll
        for (int rr = 0; rr < 4; ++rr) {          // d = dt*32 + rr*8 + hi*4 + 0..3
            ushort4 pk0, pk1;
            pk0.x = f2bf(o0[rr*4+0]*a0 + red[slot + rr*4+0]*a1);
            pk0.y = f2bf(o0[rr*4+1]*a0 + red[slot + rr*4+1]*a1);
            pk0.z = f2bf(o0[rr*4+2]*a0 + red[slot + rr*4+2]*a1);
            pk0.w = f2bf(o0[rr*4+3]*a0 + red[slot + rr*4+3]*a1);
            *(ushort4*)&aop[rr*8 + hi*4] = pk0;
            pk1.x = f2bf(o1[rr*4+0]*a0 + red[slot + 16 + rr*4+0]*a1);
            pk1.y = f2bf(o1[rr*4+1]*a0 + red[slot + 16 + rr*4+1]*a1);
            pk1.z = f2bf(o1[rr*4+2]*a0 + red[slot + 16 + rr*4+2]*a1);
            pk1.w = f2bf(o1[rr*4+3]*a0 + red[slot + 16 + rr*4+3]*a1);
            *(ushort4*)&aop[32 + rr*8 + hi*4] = pk1;
        }
    }
}

// ------- out GEMM + bias + residual: 64 rows x 256 cols per block, coalesced epilogue -------
__global__ __launch_bounds__(512) void k_out(
    const unsigned short* __restrict__ ao, const unsigned short* __restrict__ wT,
    const float* __restrict__ bout, const float* __restrict__ x,
    float* __restrict__ out) {
    __shared__ float lds_fT[256][68];             // [c][s+pad]: 69.6 KB, rows 16B-aligned
    int mt = blockIdx.x;                          // 256 blocks x 64 rows
    int tid = threadIdx.x;
    int wid = tid >> 6, lane = tid & 63;
    int g = lane >> 4, li = lane & 15;
    int rg = wid & 3, ch = wid >> 2;              // wave = 16 rows x 128 cols
    int m0 = mt * 64;
    int row = m0 + rg*16 + li;
    f32x4 acc[8];
    #pragma unroll
    for (int nt = 0; nt < 8; ++nt) acc[nt] = (f32x4){0.f,0.f,0.f,0.f};
    #pragma unroll
    for (int kt = 0; kt < 8; ++kt) {
        short8 a = *(const short8*)&ao[row*256 + kt*32 + g*8];
        #pragma unroll
        for (int nt = 0; nt < 8; ++nt) {
            int nn = ch*128 + nt*16 + li;
            short8 b = *(const short8*)&wT[nn*256 + kt*32 + g*8];
            acc[nt] = __builtin_amdgcn_mfma_f32_16x16x32_bf16(a, b, acc[nt], 0, 0, 0);
        }
    }
    #pragma unroll
    for (int nt = 0; nt < 8; ++nt) {
        int c = ch*128 + nt*16 + li;
        float bias = bout[c];
        #pragma unroll
        for (int r = 0; r < 4; ++r)
            lds_fT[c][rg*16 + g*4 + r] = acc[nt][r] + bias;
    }
    __syncthreads();
    int b = m0 >> 12;
    int s0 = m0 & 4095;
    #pragma unroll
    for (int p = 0; p < 8; ++p) {
        int c = p*32 + (tid >> 4);
        int sl = (tid & 15) * 4;
        float4 t = *(const float4*)&lds_fT[c][sl];
        int base = (b*256 + c)*4096 + s0 + sl;
        float4 xr = *(const float4*)&x[base];
        t.x += xr.x; t.y += xr.y; t.z += xr.z; t.w += xr.w;
        *(float4*)&out[base] = t;
    }
}

extern "C" void kernel_launch(void* const* d_in, const int* in_sizes, int n_in,
                              void* d_out, int out_size, void* d_ws, size_t ws_size,
                              hipStream_t stream) {
    (void)in_sizes; (void)n_in; (void)out_size; (void)ws_size;
    const float* x     = (const float*)d_in[0];
    const float* gamma = (const float*)d_in[1];
    const float* beta  = (const float*)d_in[2];
    const float* wqkv  = (const float*)d_in[3];
    const float* bqkv  = (const float*)d_in[4];
    const float* wout  = (const float*)d_in[5];
    const float* bout  = (const float*)d_in[6];
    float* out = (float*)d_out;

    char* ws = (char*)d_ws;
    unsigned short* q     = (unsigned short*)(ws + (8u<<20));         // 8 MB  [bh][S][64]
    unsigned short* kk    = (unsigned short*)(ws + (16u<<20));        // 8 MB  [bh][S][64]
    unsigned short* vT    = (unsigned short*)(ws + (24u<<20));        // 8 MB  [bh][64][S]
    unsigned short* ao    = (unsigned short*)(ws + (32u<<20));        // 8 MB  [B*S][256]
    unsigned short* wqkvT = (unsigned short*)(ws + (40u<<20));        // 384 KB [768][256]
    unsigned short* woutT = (unsigned short*)(ws + (40u<<20) + 393216);// 128 KB [256][256]
    float*          stats = (float*)(ws + (40u<<20) + 524288);        // 1 KB

    k_pre<<<320, 1024, 0, stream>>>(x, stats, wqkv, wout, wqkvT, woutT);
    k_qkvf<<<256, 512, 0, stream>>>(x, gamma, beta, stats, wqkvT, bqkv, q, kk, vT);
    k_attn<<<dim3(512), 512, 0, stream>>>(q, kk, vT, ao);
    k_out<<<dim3(256), 512, 0, stream>>>(ao, woutT, bout, x, out);
}